// Round 11
// baseline (209.890 us; speedup 1.0000x reference)
//
#include <hip/hip_runtime.h>
#include <hip/hip_bf16.h>
#include <stdint.h>

#define B_SZ 4
#define T_LEN 8192
#define D_DIM 512
#define M_TOT 32768
#define CHUNK 256   // scan chunk == GEMM M-tile
#define NCH 32      // chunks per batch
#define NCHG 128    // chunks global
#define SCS2 260    // f32 scan-tile LDS stride

typedef __attribute__((ext_vector_type(8))) short bf16x8v;
typedef __attribute__((ext_vector_type(4))) float f32x4v;

__device__ __forceinline__ unsigned short f2bf(float f) {
  unsigned int u = __float_as_uint(f);
  u += 0x7fffu + ((u >> 16) & 1u);
  return (unsigned short)(u >> 16);
}
__device__ __forceinline__ float bf2f(unsigned short b) {
  return __uint_as_float(((unsigned int)b) << 16);
}
__device__ __forceinline__ float sigmoidf_(float x) { return 1.0f / (1.0f + expf(-x)); }

// ---------------------------------------------------------------------------
// prep: blocks 0..1023 -> Wb,Wc to bf16 | block 1024 -> powA[i][ch]=a^(i+1)
//       blocks 1025.. -> x (f32) to bf16 (into d_out scratch region)
__global__ void prep_k(const float* __restrict__ x, const float* __restrict__ Wb,
                       const float* __restrict__ Wc, const float* __restrict__ A,
                       unsigned short* __restrict__ wbf, float* __restrict__ powA,
                       unsigned short* __restrict__ xbf) {
  const int b = blockIdx.x;
  const int tid = threadIdx.x;
  if (b < 1024) {
    int i = b * 256 + tid;
    wbf[i] = f2bf(Wb[i]);
    wbf[262144 + i] = f2bf(Wc[i]);
  } else if (b == 1024) {
#pragma unroll
    for (int s = 0; s < 2; ++s) {
      int ch = s * 256 + tid;
      float a = sigmoidf_(A[ch]);
      float p = a;
      for (int i = 0; i < CHUNK; ++i) {
        powA[i * D_DIM + ch] = p;
        p *= a;
      }
    }
  } else {
    size_t idx = ((size_t)(b - 1025) * 256 + tid) * 8;
    float4 v0 = *(const float4*)&x[idx];
    float4 v1 = *(const float4*)&x[idx + 4];
    uint4 o;
    o.x = (unsigned)f2bf(v0.x) | ((unsigned)f2bf(v0.y) << 16);
    o.y = (unsigned)f2bf(v0.z) | ((unsigned)f2bf(v0.w) << 16);
    o.z = (unsigned)f2bf(v1.x) | ((unsigned)f2bf(v1.y) << 16);
    o.w = (unsigned)f2bf(v1.z) | ((unsigned)f2bf(v1.w) << 16);
    *(uint4*)&xbf[idx] = o;
  }
}

// ---------------------------------------------------------------------------
// In-place chunk-carry prefix over 256-row chunks. grid=B_SZ, block=512.
__global__ void carry_k(const float* __restrict__ A, float* __restrict__ cst) {
  const int ch = threadIdx.x;
  const int bi = blockIdx.x;
  float a = sigmoidf_(A[ch]);
  float p = a;
#pragma unroll
  for (int i = 0; i < 8; ++i) p *= p;  // a^256
  float H = 0.f;
#pragma unroll 8
  for (int c = 0; c < NCH; ++c) {
    size_t off = ((size_t)bi * NCH + c) * D_DIM + ch;
    float lf = cst[off];
    cst[off] = H;
    H = fmaf(p, H, lf);
  }
}

// ---------------------------------------------------------------------------
// fix: h[g*256+t][ch] += powA[t][ch] * carry[g][ch], in place (bf16).
__global__ void fix_k(unsigned short* __restrict__ h, const float* __restrict__ cst,
                      const float* __restrict__ powA) {
  const int g = blockIdx.x;
  const int u = threadIdx.x & 63;
  const int rs = threadIdx.x >> 6;
  float car[8];
  *(float4*)car = *(const float4*)&cst[(size_t)g * D_DIM + u * 8];
  *(float4*)(car + 4) = *(const float4*)&cst[(size_t)g * D_DIM + u * 8 + 4];
#pragma unroll
  for (int p = 0; p < 32; ++p) {
    int row = p * 8 + rs;
    size_t off = ((size_t)g * CHUNK + row) * D_DIM + u * 8;
    uint4 hv = *(const uint4*)&h[off];
    float4 p0 = *(const float4*)&powA[row * D_DIM + u * 8];
    float4 p1 = *(const float4*)&powA[row * D_DIM + u * 8 + 4];
    const unsigned* hw = (const unsigned*)&hv;
    unsigned ow[4];
#pragma unroll
    for (int q = 0; q < 4; ++q) {
      float pa = (q < 2) ? ((q == 0) ? p0.x : p0.z) : ((q == 2) ? p1.x : p1.z);
      float pb = (q < 2) ? ((q == 0) ? p0.y : p0.w) : ((q == 2) ? p1.y : p1.w);
      float o0 = fmaf(pa, car[2 * q], bf2f((unsigned short)(hw[q] & 0xffff)));
      float o1 = fmaf(pb, car[2 * q + 1], bf2f((unsigned short)(hw[q] >> 16)));
      ow[q] = (unsigned)f2bf(o0) | ((unsigned)f2bf(o1) << 16);
    }
    *(uint4*)&h[off] = make_uint4(ow[0], ow[1], ow[2], ow[3]);
  }
}

// ---------------------------------------------------------------------------
// 256x256xBK64 bf16 GEMM, 8 waves (2M x 4N), 128x64 per wave.
// Staging = reg-load + ds_write with two-sided XOR swizzle (r1 pattern,
// measured 0 bank conflicts) into a double-buffered [256][64] LDS tile.
// Step: frag-read buf[cur] -> issue global loads t+1 -> MFMA -> ds_write
// buf[cur^1] -> __syncthreads (single barrier/step; compiler auto-waitcnts).
// MODE 0: epilogue = fused 256-row chunk scan -> h_local bf16 + chunk finals.
// MODE 1: epilogue = per-wave LDS-transposed coalesced f32 C store.
template <int MODE>
__global__ __launch_bounds__(512, 2) void gemm_k(
    const unsigned short* __restrict__ Abf, const unsigned short* __restrict__ Bw,
    float* __restrict__ C, const float* __restrict__ Ad,
    unsigned short* __restrict__ hOut, float* __restrict__ cst) {
  __shared__ union {
    unsigned short st[2][2][256 * 64];  // [buf][A,B][256 rows][64 k] (128 KB)
    float sc[64 * SCS2];                // MODE0 scan quarter-tile (66.6 KB)
    float tp[8][16 * 68];               // MODE1 per-wave transpose (69.6 KB)
  } sm;

  const int tid = threadIdx.x;
  const int lane = tid & 63;
  const int w = tid >> 6;     // 0..7
  const int wmi = w >> 2;     // wave M index (0..1) -> 128-row half
  const int wni = w & 3;      // wave N index (0..3) -> 64-col slice
  const int wn = wni * 64;

  // bijective XCD swizzle (grid 256 = 8*32); work = mt*2 + ntile
  const int flat = blockIdx.y * 2 + blockIdx.x;
  const int work = ((flat & 7) << 5) | (flat >> 3);
  const int mt = work >> 1;   // M-tile == scan chunk id (0..127)
  const int bm = mt * 256;
  const int bn = (work & 1) * 256;

  const int l15 = lane & 15;
  const int g4 = lane >> 4;
  const int srow = tid >> 3;        // staging row base (tid-major)
  const int sck = tid & 7;          // staging 16B-chunk within row

  uint4 aR[4], bR[4];  // staged registers for next K-tile

  auto loadG = [&](int k0) {
#pragma unroll
    for (int q = 0; q < 4; ++q) {
      int row = q * 64 + srow;
      aR[q] = *(const uint4*)&Abf[(size_t)(bm + row) * 512 + k0 + sck * 8];
      bR[q] = *(const uint4*)&Bw[(size_t)(bn + row) * 512 + k0 + sck * 8];
    }
  };

  auto writeS = [&](int buf) {
#pragma unroll
    for (int q = 0; q < 4; ++q) {
      int row = q * 64 + srow;
      int byte = row * 128 + ((sck * 16) ^ ((row & 7) << 4));
      *(uint4*)((char*)sm.st[buf][0] + byte) = aR[q];
      *(uint4*)((char*)sm.st[buf][1] + byte) = bR[q];
    }
  };

  f32x4v acc[8][4] = {};

  // prologue: stage tile 0
  loadG(0);
  writeS(0);
  __syncthreads();

#pragma unroll
  for (int t = 0; t < 8; ++t) {
    const int cur = t & 1;
    if (t < 7) loadG((t + 1) * 64);  // loads fly under frag reads + MFMA
#pragma unroll
    for (int ks = 0; ks < 2; ++ks) {
      bf16x8v af[8], bf_[4];
#pragma unroll
      for (int i = 0; i < 8; ++i) {
        int row = wmi * 128 + i * 16 + l15;
        int byte = row * 128 + ((ks * 64 + g4 * 16) ^ ((row & 7) << 4));
        af[i] = *(const bf16x8v*)((const char*)sm.st[cur][0] + byte);
      }
#pragma unroll
      for (int j = 0; j < 4; ++j) {
        int row = wn + j * 16 + l15;
        int byte = row * 128 + ((ks * 64 + g4 * 16) ^ ((row & 7) << 4));
        bf_[j] = *(const bf16x8v*)((const char*)sm.st[cur][1] + byte);
      }
      __builtin_amdgcn_s_setprio(1);
#pragma unroll
      for (int i = 0; i < 8; ++i)
#pragma unroll
        for (int j = 0; j < 4; ++j)
          acc[i][j] = __builtin_amdgcn_mfma_f32_16x16x32_bf16(af[i], bf_[j], acc[i][j], 0, 0, 0);
      __builtin_amdgcn_s_setprio(0);
    }
    if (t < 7) writeS(cur ^ 1);  // compiler inserts vmcnt before reg use
    __syncthreads();             // writes visible; buf[cur] free for t+1's write
  }

  if constexpr (MODE == 0) {
    // fused 256-row chunk scan, four 64-row quarters; 256 channels/block-half
    float a = 0.f, hcar = 0.f;
    if (tid < 256) a = sigmoidf_(Ad[bn + tid]);
#pragma unroll
    for (int q = 0; q < 4; ++q) {
      if (wmi == (q >> 1)) {  // waves owning these 64 rows scatter acc
        int i0 = (q & 1) * 4;
#pragma unroll
        for (int ii = 0; ii < 4; ++ii)
#pragma unroll
          for (int j = 0; j < 4; ++j)
#pragma unroll
            for (int r = 0; r < 4; ++r)
              sm.sc[(ii * 16 + g4 * 4 + r) * SCS2 + wn + j * 16 + l15] = acc[i0 + ii][j][r];
      }
      __syncthreads();
      if (tid < 256) {
        float h = hcar;
#pragma unroll 8
        for (int tt = 0; tt < 64; ++tt) {
          h = fmaf(a, h, sm.sc[tt * SCS2 + tid]);
          sm.sc[tt * SCS2 + tid] = h;
        }
        hcar = h;
      }
      __syncthreads();
      // write this quarter's 64 rows x 256 ch as bf16 (coalesced uint4)
#pragma unroll
      for (int p = 0; p < 4; ++p) {
        int uu = p * 512 + tid;
        int row = uu >> 5, c8 = (uu & 31) * 8;
        const float* s = &sm.sc[row * SCS2 + c8];
        unsigned w0 = (unsigned)f2bf(s[0]) | ((unsigned)f2bf(s[1]) << 16);
        unsigned w1 = (unsigned)f2bf(s[2]) | ((unsigned)f2bf(s[3]) << 16);
        unsigned w2 = (unsigned)f2bf(s[4]) | ((unsigned)f2bf(s[5]) << 16);
        unsigned w3 = (unsigned)f2bf(s[6]) | ((unsigned)f2bf(s[7]) << 16);
        *(uint4*)&hOut[(size_t)(bm + q * 64 + row) * D_DIM + bn + c8] =
            make_uint4(w0, w1, w2, w3);
      }
      __syncthreads();
    }
    if (tid < 256) cst[(size_t)mt * D_DIM + bn + tid] = hcar;  // chunk-local final
  } else {
    // coalesced C store via per-wave LDS transpose (16x68 region per wave)
    float* tp = sm.tp[w];
#pragma unroll
    for (int i = 0; i < 8; ++i) {
#pragma unroll
      for (int j = 0; j < 4; ++j)
#pragma unroll
        for (int r = 0; r < 4; ++r)
          tp[(g4 * 4 + r) * 68 + j * 16 + l15] = acc[i][j][r];
#pragma unroll
      for (int p = 0; p < 4; ++p) {
        f32x4v v = *(const f32x4v*)&tp[(p * 4 + g4) * 68 + l15 * 4];
        *(f32x4v*)&C[(size_t)(bm + wmi * 128 + i * 16 + p * 4 + g4) * 512 + bn + wn + l15 * 4] = v;
      }
    }
  }
}

// ---------------------------------------------------------------------------
extern "C" void kernel_launch(void* const* d_in, const int* in_sizes, int n_in,
                              void* d_out, int out_size, void* d_ws, size_t ws_size,
                              hipStream_t stream) {
  const float* x = (const float*)d_in[0];
  const float* W_B = (const float*)d_in[1];
  const float* W_C = (const float*)d_in[2];
  const float* A = (const float*)d_in[3];
  float* out = (float*)d_out;
  char* ws = (char*)d_ws;

  // ws: [0,512K) Wb | [512K,1M) Wc | [1M,1.5M) powA[256][512] f32 |
  //     [1.5M,1.75M) cst[128][512] f32 | [2M,34M) h_local bf16.
  // x_bf16 lives in d_out (dead before GEMM2's C-write).
  unsigned short* Wb = (unsigned short*)ws;
  unsigned short* Wc = Wb + 262144;
  float* powA = (float*)(ws + 0x100000);
  float* cst = (float*)(ws + 0x180000);
  unsigned short* hbf = (unsigned short*)(ws + 0x200000);
  unsigned short* xbf = (unsigned short*)d_out;

  prep_k<<<1025 + 8192, 256, 0, stream>>>(x, W_B, W_C, A, Wb, powA, xbf);

  dim3 gg(2, 128);  // 256 blocks = 1/CU
  gemm_k<0><<<gg, 512, 0, stream>>>(xbf, Wb, nullptr, A, hbf, cst);
  carry_k<<<B_SZ, 512, 0, stream>>>(A, cst);
  fix_k<<<NCHG, 512, 0, stream>>>(hbf, cst, powA);
  gemm_k<1><<<gg, 512, 0, stream>>>(hbf, Wc, out, A, nullptr, cst);
}

// Round 12
// 163.346 us; speedup vs baseline: 1.2849x; 1.2849x over previous
//
#include <hip/hip_runtime.h>
#include <hip/hip_bf16.h>
#include <stdint.h>

#define B_SZ 4
#define T_LEN 8192
#define D_DIM 512
#define M_TOT 32768
#define CHUNK 128
#define NCH 64    // chunks per batch
#define SCS 132   // f32 scan-tile LDS stride

typedef __attribute__((ext_vector_type(8))) short bf16x8v;
typedef __attribute__((ext_vector_type(4))) float f32x4v;

__device__ __forceinline__ unsigned short f2bf(float f) {
  unsigned int u = __float_as_uint(f);
  u += 0x7fffu + ((u >> 16) & 1u);
  return (unsigned short)(u >> 16);
}
__device__ __forceinline__ float bf2f(unsigned short b) {
  return __uint_as_float(((unsigned int)b) << 16);
}
__device__ __forceinline__ float sigmoidf_(float x) { return 1.0f / (1.0f + expf(-x)); }

// ---------------------------------------------------------------------------
// prep: blocks 0..1023 -> Wb,Wc to bf16 | block 1024 -> powA[i][ch]=a^(i+1)
//       blocks 1025.. -> x (f32) to bf16 (into d_out scratch region)
__global__ void prep_k(const float* __restrict__ x, const float* __restrict__ Wb,
                       const float* __restrict__ Wc, const float* __restrict__ A,
                       unsigned short* __restrict__ wbf, float* __restrict__ powA,
                       unsigned short* __restrict__ xbf) {
  const int b = blockIdx.x;
  const int tid = threadIdx.x;
  if (b < 1024) {
    int i = b * 256 + tid;
    wbf[i] = f2bf(Wb[i]);
    wbf[262144 + i] = f2bf(Wc[i]);
  } else if (b == 1024) {
#pragma unroll
    for (int s = 0; s < 2; ++s) {
      int ch = s * 256 + tid;
      float a = sigmoidf_(A[ch]);
      float p = a;
      for (int i = 0; i < CHUNK; ++i) {
        powA[i * D_DIM + ch] = p;
        p *= a;
      }
    }
  } else {
    size_t idx = ((size_t)(b - 1025) * 256 + tid) * 8;
    float4 v0 = *(const float4*)&x[idx];
    float4 v1 = *(const float4*)&x[idx + 4];
    uint4 o;
    o.x = (unsigned)f2bf(v0.x) | ((unsigned)f2bf(v0.y) << 16);
    o.y = (unsigned)f2bf(v0.z) | ((unsigned)f2bf(v0.w) << 16);
    o.z = (unsigned)f2bf(v1.x) | ((unsigned)f2bf(v1.y) << 16);
    o.w = (unsigned)f2bf(v1.z) | ((unsigned)f2bf(v1.w) << 16);
    *(uint4*)&xbf[idx] = o;
  }
}

// ---------------------------------------------------------------------------
// In-place chunk-carry prefix. grid=B_SZ, block=512.
__global__ void carry_k(const float* __restrict__ A, float* __restrict__ cst) {
  const int ch = threadIdx.x;
  const int bi = blockIdx.x;
  float a = sigmoidf_(A[ch]);
  float p = a;
#pragma unroll
  for (int i = 0; i < 7; ++i) p *= p;  // a^128
  float H = 0.f;
#pragma unroll 8
  for (int c = 0; c < NCH; ++c) {
    size_t off = ((size_t)bi * NCH + c) * D_DIM + ch;
    float lf = cst[off];
    cst[off] = H;
    H = fmaf(p, H, lf);
  }
}

// ---------------------------------------------------------------------------
// fix: h[g*128+t][ch] += powA[t][ch] * carry[g][ch], in place (bf16).
__global__ void fix_k(unsigned short* __restrict__ h, const float* __restrict__ cst,
                      const float* __restrict__ powA) {
  const int g = blockIdx.x;
  const int u = threadIdx.x & 63;
  const int rs = threadIdx.x >> 6;
  float car[8];
  *(float4*)car = *(const float4*)&cst[(size_t)g * D_DIM + u * 8];
  *(float4*)(car + 4) = *(const float4*)&cst[(size_t)g * D_DIM + u * 8 + 4];
#pragma unroll
  for (int p = 0; p < 16; ++p) {
    int row = p * 8 + rs;
    size_t off = ((size_t)g * CHUNK + row) * D_DIM + u * 8;
    uint4 hv = *(const uint4*)&h[off];
    float4 p0 = *(const float4*)&powA[row * D_DIM + u * 8];
    float4 p1 = *(const float4*)&powA[row * D_DIM + u * 8 + 4];
    const unsigned* hw = (const unsigned*)&hv;
    unsigned ow[4];
#pragma unroll
    for (int q = 0; q < 4; ++q) {
      float pa = (q < 2) ? ((q == 0) ? p0.x : p0.z) : ((q == 2) ? p1.x : p1.z);
      float pb = (q < 2) ? ((q == 0) ? p0.y : p0.w) : ((q == 2) ? p1.y : p1.w);
      float o0 = fmaf(pa, car[2 * q], bf2f((unsigned short)(hw[q] & 0xffff)));
      float o1 = fmaf(pb, car[2 * q + 1], bf2f((unsigned short)(hw[q] >> 16)));
      ow[q] = (unsigned)f2bf(o0) | ((unsigned)f2bf(o1) << 16);
    }
    *(uint4*)&h[off] = make_uint4(ow[0], ow[1], ow[2], ow[3]);
  }
}

// ---------------------------------------------------------------------------
// 128x128 bf16 GEMM with NO LDS in the K-loop: each wave loads its MFMA A/B
// fragments directly from global (L2/L3-resident; 16 fully-consumed 64B lines
// per 64-lane load = same line count as coalesced). No barriers, no staging:
// waves run free, 4 blocks/CU hide L2 latency. LDS used only by epilogues.
// MODE 0: epilogue = fused chunk scan -> h_local bf16 + chunk finals.
// MODE 1: epilogue = per-wave LDS-transposed coalesced f32 C store.
template <int MODE>
__global__ __launch_bounds__(256, 2) void gemm_k(
    const unsigned short* __restrict__ Abf, const unsigned short* __restrict__ Bw,
    float* __restrict__ C, const float* __restrict__ Ad,
    unsigned short* __restrict__ hOut, float* __restrict__ cst) {
  __shared__ union {
    float sc[64 * SCS];    // MODE0 scan half-tile (33.8 KB)
    float tp[4][16 * 68];  // MODE1 per-wave transpose (17.4 KB)
  } sm;

  const int tid = threadIdx.x;
  const int lane = tid & 63;
  const int w = tid >> 6;
  const int wm = (w >> 1) * 64;
  const int wn = (w & 1) * 64;

  // bijective XCD swizzle (grid 1024 = 8*128), n-major within XCD
  const int flat = blockIdx.y * 4 + blockIdx.x;
  const int work = ((flat & 7) << 7) | (flat >> 3);
  const int mt = work >> 2;
  const int bm = mt * 128;
  const int bn = (work & 3) * 128;

  const int l15 = lane & 15;
  const int g4 = lane >> 4;

  // per-lane fragment bases: row = base + i*16 + l15, k-oct = g4
  const unsigned short* aB = Abf + (size_t)(bm + wm + l15) * 512 + g4 * 8;
  const unsigned short* bB = Bw + (size_t)(bn + wn + l15) * 512 + g4 * 8;

  f32x4v acc[4][4] = {};

#pragma unroll 2
  for (int t = 0; t < 16; ++t) {  // K=512 in 32-steps
    const int k = t * 32;
    bf16x8v af[4], bf_[4];
#pragma unroll
    for (int i = 0; i < 4; ++i)
      af[i] = *(const bf16x8v*)&aB[(size_t)i * 16 * 512 + k];
#pragma unroll
    for (int j = 0; j < 4; ++j)
      bf_[j] = *(const bf16x8v*)&bB[(size_t)j * 16 * 512 + k];
#pragma unroll
    for (int i = 0; i < 4; ++i)
#pragma unroll
      for (int j = 0; j < 4; ++j)
        acc[i][j] = __builtin_amdgcn_mfma_f32_16x16x32_bf16(af[i], bf_[j], acc[i][j], 0, 0, 0);
  }

  if constexpr (MODE == 0) {
    // fused chunk-local scan, two 64-row halves
    float a = 0.f, hcar = 0.f;
    if (tid < 128) a = sigmoidf_(Ad[bn + tid]);
#pragma unroll
    for (int half = 0; half < 2; ++half) {
      if ((w >> 1) == half) {
#pragma unroll
        for (int i = 0; i < 4; ++i)
#pragma unroll
          for (int j = 0; j < 4; ++j)
#pragma unroll
            for (int r = 0; r < 4; ++r)
              sm.sc[(i * 16 + g4 * 4 + r) * SCS + wn + j * 16 + l15] = acc[i][j][r];
      }
      __syncthreads();
      if (tid < 128) {
        float h = hcar;
#pragma unroll 8
        for (int t = 0; t < 64; ++t) {
          h = fmaf(a, h, sm.sc[t * SCS + tid]);
          sm.sc[t * SCS + tid] = h;
        }
        hcar = h;
      }
      __syncthreads();
#pragma unroll
      for (int p = 0; p < 4; ++p) {
        int uu = p * 256 + tid;
        int row = uu >> 4, c8 = (uu & 15) * 8;
        const float* s = &sm.sc[row * SCS + c8];
        unsigned w0 = (unsigned)f2bf(s[0]) | ((unsigned)f2bf(s[1]) << 16);
        unsigned w1 = (unsigned)f2bf(s[2]) | ((unsigned)f2bf(s[3]) << 16);
        unsigned w2 = (unsigned)f2bf(s[4]) | ((unsigned)f2bf(s[5]) << 16);
        unsigned w3 = (unsigned)f2bf(s[6]) | ((unsigned)f2bf(s[7]) << 16);
        *(uint4*)&hOut[(size_t)(bm + half * 64 + row) * D_DIM + bn + c8] =
            make_uint4(w0, w1, w2, w3);
      }
      __syncthreads();
    }
    if (tid < 128) cst[(size_t)mt * D_DIM + bn + tid] = hcar;
  } else {
    // coalesced C store via per-wave LDS transpose
    float* tp = sm.tp[w];
#pragma unroll
    for (int i = 0; i < 4; ++i) {
#pragma unroll
      for (int j = 0; j < 4; ++j)
#pragma unroll
        for (int r = 0; r < 4; ++r)
          tp[(g4 * 4 + r) * 68 + j * 16 + l15] = acc[i][j][r];
#pragma unroll
      for (int p = 0; p < 4; ++p) {
        f32x4v v = *(const f32x4v*)&tp[(p * 4 + g4) * 68 + l15 * 4];
        *(f32x4v*)&C[(size_t)(bm + wm + i * 16 + p * 4 + g4) * 512 + bn + wn + l15 * 4] = v;
      }
    }
  }
}

// ---------------------------------------------------------------------------
extern "C" void kernel_launch(void* const* d_in, const int* in_sizes, int n_in,
                              void* d_out, int out_size, void* d_ws, size_t ws_size,
                              hipStream_t stream) {
  const float* x = (const float*)d_in[0];
  const float* W_B = (const float*)d_in[1];
  const float* W_C = (const float*)d_in[2];
  const float* A = (const float*)d_in[3];
  float* out = (float*)d_out;
  char* ws = (char*)d_ws;

  // ws: [0,512K) Wb | [512K,1M) Wc | [1M,1.25M) powA | [1.25M,1.75M) cst |
  //     [2M,34M) h_local bf16.  x_bf16 lives in d_out (dead before GEMM2's C-write).
  unsigned short* Wb = (unsigned short*)ws;
  unsigned short* Wc = Wb + 262144;
  float* powA = (float*)(ws + 0x100000);
  float* cst = (float*)(ws + 0x140000);
  unsigned short* hbf = (unsigned short*)(ws + 0x200000);
  unsigned short* xbf = (unsigned short*)d_out;

  prep_k<<<1025 + 8192, 256, 0, stream>>>(x, W_B, W_C, A, Wb, powA, xbf);

  dim3 gg(D_DIM / 128, M_TOT / 128);  // (4, 256)
  gemm_k<0><<<gg, 256, 0, stream>>>(xbf, Wb, nullptr, A, hbf, cst);
  carry_k<<<B_SZ, 512, 0, stream>>>(A, cst);
  fix_k<<<256, 512, 0, stream>>>(hbf, cst, powA);
  gemm_k<1><<<gg, 256, 0, stream>>>(hbf, Wc, out, A, nullptr, cst);
}

// Round 13
// 121.585 us; speedup vs baseline: 1.7263x; 1.3435x over previous
//
#include <hip/hip_runtime.h>
#include <hip/hip_bf16.h>
#include <stdint.h>

#define B_SZ 4
#define T_LEN 8192
#define D_DIM 512
#define M_TOT 32768
#define RB 64      // gemm M-tile == scan chunk (rows)
#define NCH 128    // chunks per batch (T/64)
#define SCS 260    // f32 LDS stride for scan tile

typedef __attribute__((ext_vector_type(8))) short bf16x8v;
typedef __attribute__((ext_vector_type(4))) float f32x4v;

__device__ __forceinline__ unsigned short f2bf(float f) {
  unsigned int u = __float_as_uint(f);
  u += 0x7fffu + ((u >> 16) & 1u);
  return (unsigned short)(u >> 16);
}
__device__ __forceinline__ float bf2f(unsigned short b) {
  return __uint_as_float(((unsigned int)b) << 16);
}
__device__ __forceinline__ float sigmoidf_(float x) { return 1.0f / (1.0f + expf(-x)); }

// ---------------------------------------------------------------------------
// Fragment-chunk layout: matrix [R][512] is stored as chunks of 16 rows x 32 k.
// chunk id = rowblk*16 + kslice; within a chunk, lane l holds 8 bf16 at
// (row = rowblk*16 + (l&15), k = kslice*32 + (l>>4)*8 .. +8)  ->  every MFMA
// fragment load is chunkbase + lane*16: 1KB contiguous, perfectly coalesced.
//
// prep: blocks 0..2047 pack x (f32 -> bf16), 2048..2079 Wb, 2080..2111 Wc,
//       block 2112 -> powA[i][ch] = a^(i+1), i<64 (row-major).
__global__ void prep_k(const float* __restrict__ x, const float* __restrict__ Wb,
                       const float* __restrict__ Wc, const float* __restrict__ A,
                       unsigned short* __restrict__ wpk, float* __restrict__ powA,
                       unsigned short* __restrict__ xpk) {
  const int b = blockIdx.x;
  const int tid = threadIdx.x;
  if (b == 2112) {
#pragma unroll
    for (int s = 0; s < 2; ++s) {
      int ch = s * 256 + tid;
      float a = sigmoidf_(A[ch]);
      float p = a;
      for (int i = 0; i < RB; ++i) {
        powA[i * D_DIM + ch] = p;
        p *= a;
      }
    }
    return;
  }
  __shared__ unsigned short sd[16 * 520];  // 16 rows x 512 cols bf16, padded
  const float* src;
  unsigned short* dst;
  if (b < 2048) {
    src = x + (size_t)b * 8192;
    dst = xpk + (size_t)b * 8192;
  } else if (b < 2080) {
    int r = b - 2048;
    src = Wb + (size_t)r * 8192;
    dst = wpk + (size_t)r * 8192;
  } else {
    int r = b - 2080;
    src = Wc + (size_t)r * 8192;
    dst = wpk + 262144 + (size_t)r * 8192;
  }
  // coalesced f32 read + convert -> padded LDS
#pragma unroll
  for (int it = 0; it < 4; ++it) {
    int idx = (it * 256 + tid) * 8;
    int row = idx >> 9, col = idx & 511;
    float4 v0 = *(const float4*)&src[row * 512 + col];
    float4 v1 = *(const float4*)&src[row * 512 + col + 4];
    uint4 o;
    o.x = (unsigned)f2bf(v0.x) | ((unsigned)f2bf(v0.y) << 16);
    o.y = (unsigned)f2bf(v0.z) | ((unsigned)f2bf(v0.w) << 16);
    o.z = (unsigned)f2bf(v1.x) | ((unsigned)f2bf(v1.y) << 16);
    o.w = (unsigned)f2bf(v1.z) | ((unsigned)f2bf(v1.w) << 16);
    *(uint4*)&sd[row * 520 + col] = o;
  }
  __syncthreads();
  // fragment-order gather from LDS (2-way banks via 520 pad) -> coalesced write
#pragma unroll
  for (int it = 0; it < 4; ++it) {
    int idx = it * 256 + tid;
    int cs = idx >> 6, l = idx & 63;
    uint4 v = *(const uint4*)&sd[(l & 15) * 520 + cs * 32 + (l >> 4) * 8];
    *(uint4*)&dst[(size_t)cs * 512 + l * 8] = v;
  }
}

// ---------------------------------------------------------------------------
// In-place chunk-carry prefix over 64-row chunks. grid=B_SZ, block=512.
__global__ void carry_k(const float* __restrict__ A, float* __restrict__ cst) {
  const int ch = threadIdx.x;
  const int bi = blockIdx.x;
  float a = sigmoidf_(A[ch]);
  float p = a;
#pragma unroll
  for (int i = 0; i < 6; ++i) p *= p;  // a^64
  float H = 0.f;
#pragma unroll 4
  for (int c = 0; c < NCH; ++c) {
    size_t off = ((size_t)bi * NCH + c) * D_DIM + ch;
    float lf = cst[off];
    cst[off] = H;
    H = fmaf(p, H, lf);
  }
}

// ---------------------------------------------------------------------------
// fix on PACKED h: chunk (rowblk rb, kslice cs): row = rb*16+(l&15),
// ch = cs*32+(l>>4)*8+e.  h += powA[row&63][ch] * carry[rb>>2][ch].
// grid = 2048 rowblks, block = 512.
__global__ void fix_k(unsigned short* __restrict__ h, const float* __restrict__ cst,
                      const float* __restrict__ powA) {
  const int rb = blockIdx.x;
  const int g = rb >> 2;          // global 64-row chunk
  const int r0 = (rb & 3) * 16;   // row offset within chunk
#pragma unroll
  for (int it = 0; it < 2; ++it) {
    int idx = it * 512 + threadIdx.x;
    int cs = idx >> 6, l = idx & 63;
    int row64 = r0 + (l & 15);
    int chb = cs * 32 + (l >> 4) * 8;
    size_t off = ((size_t)rb * 16 + cs) * 512 + l * 8;
    uint4 hv = *(const uint4*)&h[off];
    float4 p0 = *(const float4*)&powA[row64 * 512 + chb];
    float4 p1 = *(const float4*)&powA[row64 * 512 + chb + 4];
    float4 c0 = *(const float4*)&cst[(size_t)g * 512 + chb];
    float4 c1 = *(const float4*)&cst[(size_t)g * 512 + chb + 4];
    const unsigned* hw = (const unsigned*)&hv;
    float pf[8] = {p0.x, p0.y, p0.z, p0.w, p1.x, p1.y, p1.z, p1.w};
    float cf[8] = {c0.x, c0.y, c0.z, c0.w, c1.x, c1.y, c1.z, c1.w};
    unsigned ow[4];
#pragma unroll
    for (int q = 0; q < 4; ++q) {
      float o0 = fmaf(pf[2 * q], cf[2 * q], bf2f((unsigned short)(hw[q] & 0xffff)));
      float o1 = fmaf(pf[2 * q + 1], cf[2 * q + 1], bf2f((unsigned short)(hw[q] >> 16)));
      ow[q] = (unsigned)f2bf(o0) | ((unsigned)f2bf(o1) << 16);
    }
    *(uint4*)&h[off] = make_uint4(ow[0], ow[1], ow[2], ow[3]);
  }
}

// ---------------------------------------------------------------------------
// 64x512 (full-N) bf16 GEMM on PACKED operands. 8 waves (2M x 4N), wave tile
// 32x128. K-loop: NO LDS, NO barriers, NO staging — A and B fragments loaded
// directly from global (1KB coalesced each); A is HBM-streamed once, B (the
// 512KB packed weight) is L1/L2-hot and shared by all blocks. Grid = 512
// blocks (2/CU, all co-resident). LDS is used only by the epilogues.
// MODE 0: epilogue = fused 64-row chunk scan -> packed h bf16 + chunk finals.
// MODE 1: epilogue = per-wave LDS-transposed coalesced f32 C store.
template <int MODE>
__global__ __launch_bounds__(512, 2) void gemm_k(
    const unsigned short* __restrict__ Apk, const unsigned short* __restrict__ Bpk,
    float* __restrict__ C, const float* __restrict__ Ad,
    unsigned short* __restrict__ hOut, float* __restrict__ cst) {
  __shared__ union {
    float sc[RB * SCS];     // MODE0 scan half (64 x 260 f32 = 66.6 KB)
    float tp[8][16 * 132];  // MODE1 per-wave transpose (67.6 KB)
  } sm;

  const int tid = threadIdx.x;
  const int lane = tid & 63;
  const int w = tid >> 6;   // 0..7
  const int wmi = w >> 2;   // M half (32 rows)
  const int wni = w & 3;    // N quarter (128 cols)
  const int mt = blockIdx.x;  // 64-row tile == scan chunk id (0..511)

  const int l15 = lane & 15;
  const int g4 = lane >> 4;

  // fragment-chunk bases (chunk = 1KB = 512 shorts; rowblk stride = 16*512)
  const unsigned short* aB = Apk + ((size_t)(mt * 4 + wmi * 2) * 16) * 512 + lane * 8;
  const unsigned short* bB = Bpk + ((size_t)(wni * 8) * 16) * 512 + lane * 8;

  f32x4v acc[2][8] = {};

#pragma unroll 2
  for (int t = 0; t < 16; ++t) {
    bf16x8v af[2], bf_[8];
#pragma unroll
    for (int i = 0; i < 2; ++i)
      af[i] = *(const bf16x8v*)&aB[(size_t)i * 8192 + t * 512];
#pragma unroll
    for (int j = 0; j < 8; ++j)
      bf_[j] = *(const bf16x8v*)&bB[(size_t)j * 8192 + t * 512];
#pragma unroll
    for (int i = 0; i < 2; ++i)
#pragma unroll
      for (int j = 0; j < 8; ++j)
        acc[i][j] = __builtin_amdgcn_mfma_f32_16x16x32_bf16(af[i], bf_[j], acc[i][j], 0, 0, 0);
  }
  __syncthreads();  // K-loop done; LDS free for epilogue

  if constexpr (MODE == 0) {
    // fused 64-row chunk scan over all 512 channels, two 256-ch halves
#pragma unroll
    for (int hf = 0; hf < 2; ++hf) {
      if ((wni >> 1) == hf) {  // waves owning these 256 cols scatter acc
        int c0 = (wni & 1) * 128;
#pragma unroll
        for (int i = 0; i < 2; ++i)
#pragma unroll
          for (int j = 0; j < 8; ++j)
#pragma unroll
            for (int r = 0; r < 4; ++r)
              sm.sc[(wmi * 32 + i * 16 + g4 * 4 + r) * SCS + c0 + j * 16 + l15] = acc[i][j][r];
      }
      __syncthreads();
      if (tid < 256) {
        float a2 = sigmoidf_(Ad[hf * 256 + tid]);
        float h = 0.f;
#pragma unroll 8
        for (int tt = 0; tt < RB; ++tt) {
          h = fmaf(a2, h, sm.sc[tt * SCS + tid]);
          sm.sc[tt * SCS + tid] = h;
        }
        cst[(size_t)mt * 512 + hf * 256 + tid] = h;  // chunk-local final
      }
      __syncthreads();
      // write h_local PACKED (chunks: rbl 0..3 x cs 0..7 within this half)
#pragma unroll
      for (int p = 0; p < 4; ++p) {
        int idx = p * 512 + tid;
        int cl = idx >> 6, l = idx & 63;
        int rbl = cl >> 3, cs = cl & 7;
        const float* s = &sm.sc[(rbl * 16 + (l & 15)) * SCS + cs * 32 + (l >> 4) * 8];
        unsigned w0 = (unsigned)f2bf(s[0]) | ((unsigned)f2bf(s[1]) << 16);
        unsigned w1 = (unsigned)f2bf(s[2]) | ((unsigned)f2bf(s[3]) << 16);
        unsigned w2 = (unsigned)f2bf(s[4]) | ((unsigned)f2bf(s[5]) << 16);
        unsigned w3 = (unsigned)f2bf(s[6]) | ((unsigned)f2bf(s[7]) << 16);
        *(uint4*)&hOut[(((size_t)mt * 4 + rbl) * 16 + hf * 8 + cs) * 512 + l * 8] =
            make_uint4(w0, w1, w2, w3);
      }
      __syncthreads();
    }
  } else {
    // coalesced C store via per-wave LDS transpose (16 x 132 region per wave)
    float* tp = sm.tp[w];
#pragma unroll
    for (int i = 0; i < 2; ++i) {
#pragma unroll
      for (int j = 0; j < 8; ++j)
#pragma unroll
        for (int r = 0; r < 4; ++r)
          tp[(g4 * 4 + r) * 132 + j * 16 + l15] = acc[i][j][r];
#pragma unroll
      for (int p = 0; p < 8; ++p) {
        int row = p * 2 + (lane >> 5);
        int slot = lane & 31;
        f32x4v v = *(const f32x4v*)&tp[row * 132 + slot * 4];
        *(f32x4v*)&C[(size_t)(mt * 64 + wmi * 32 + i * 16 + row) * 512 + wni * 128 + slot * 4] = v;
      }
    }
  }
}

// ---------------------------------------------------------------------------
extern "C" void kernel_launch(void* const* d_in, const int* in_sizes, int n_in,
                              void* d_out, int out_size, void* d_ws, size_t ws_size,
                              hipStream_t stream) {
  const float* x = (const float*)d_in[0];
  const float* W_B = (const float*)d_in[1];
  const float* W_C = (const float*)d_in[2];
  const float* A = (const float*)d_in[3];
  float* out = (float*)d_out;
  char* ws = (char*)d_ws;

  // ws: [0,1M) Wpk (Wb|Wc) | [1M,1.125M) powA[64][512] f32 |
  //     [1.125M+pad: 1.125M..2.125M) cst[512][512] f32 | [2.125M, +33.6M) h packed.
  // xpk (33.6MB) lives in d_out — dead before GEMM2's C-write.
  unsigned short* Wpk = (unsigned short*)ws;
  float* powA = (float*)(ws + 0x100000);
  float* cst = (float*)(ws + 0x120000);
  unsigned short* hpk = (unsigned short*)(ws + 0x220000);
  unsigned short* xpk = (unsigned short*)d_out;

  prep_k<<<2113, 256, 0, stream>>>(x, W_B, W_C, A, Wpk, powA, xpk);

  gemm_k<0><<<512, 512, 0, stream>>>(xpk, Wpk, nullptr, A, hpk, cst);
  carry_k<<<B_SZ, 512, 0, stream>>>(A, cst);
  fix_k<<<2048, 512, 0, stream>>>(hpk, cst, powA);
  gemm_k<1><<<512, 512, 0, stream>>>(hpk, Wpk + 262144, out, A, nullptr, cst);
}